// Round 15
// baseline (112.380 us; speedup 1.0000x reference)
//
#include <hip/hip_runtime.h>
#include <hip/hip_bf16.h>
#include <math.h>

typedef __bf16 bf16;
typedef __bf16 bf16x8 __attribute__((ext_vector_type(8)));
typedef __bf16 bf16x4 __attribute__((ext_vector_type(4)));
typedef float f32x4 __attribute__((ext_vector_type(4)));
typedef unsigned short u16;
typedef u16 u16x8 __attribute__((ext_vector_type(8)));

#define SEQ 1024
#define DIMSZ 1024
#define NHEADS 16
#define HEADDIM 64
#define BATCH 4
#define MTOK (BATCH * SEQ)

// q-scale: 1/sqrt(64) * log2(e)  (log2e folded so softmax uses raw exp2)
#define QSCALE 0.180336880f

// ---------------- async global->LDS (16B per lane, linear dest) ----------------
typedef __attribute__((address_space(1))) const unsigned char gas_u8;
typedef __attribute__((address_space(3))) unsigned char las_u8;
__device__ __forceinline__ void gload16(const void* g, void* l) {
    __builtin_amdgcn_global_load_lds((const gas_u8*)g, (las_u8*)l, 16, 0, 0);
}

// ---------------- fp32 -> bf16 conversion with baked chunk-swizzle ----------------
// dst element (row, col) stored at chunk ^= (row&7) within each 64-col group
__device__ __forceinline__ void cvt_store(const float4 v, bf16* dst, int e0, float scale) {
    int row = e0 >> 10, col = e0 & 1023;
    int col2 = (col & ~63) | (col & 7) | (((((col >> 3) & 7) ^ (row & 7))) << 3);
    bf16x4 o;
    o[0] = (bf16)(v.x * scale);
    o[1] = (bf16)(v.y * scale);
    o[2] = (bf16)(v.z * scale);
    o[3] = (bf16)(v.w * scale);
    *reinterpret_cast<bf16x4*>(&dst[(size_t)row * 1024 + col2]) = o;
}

// single merged conversion launch: x -> xb; wq(*QSCALE),wk,wv -> wqkvb; wo -> wob
__global__ void cvt_all(const float4* __restrict__ x,
                        const float4* __restrict__ wq, const float4* __restrict__ wk,
                        const float4* __restrict__ wv, const float4* __restrict__ wo,
                        bf16* __restrict__ xb, bf16* __restrict__ wqkvb,
                        bf16* __restrict__ wob) {
    int i = blockIdx.x * blockDim.x + threadIdx.x;   // 0 .. 2*1048576-1
    if (i < 1048576) {
        cvt_store(x[i], xb, i << 2, 1.f);
    } else {
        int li = i - 1048576;
        int mat = li >> 18, lj = li & 262143;
        const float4* s = (mat == 0) ? wq : (mat == 1) ? wk : (mat == 2) ? wv : wo;
        bf16* d = (mat < 3) ? (wqkvb + (size_t)mat * 1024 * 1024) : wob;
        cvt_store(s[lj], d, lj << 2, (mat == 0) ? QSCALE : 1.f);
    }
}

// swizzled LDS fragment read from linear [rows][64] bf16 tile (128B rows)
__device__ __forceinline__ bf16x8 fragswz(const bf16* base, int row, int kb) {
    return *reinterpret_cast<const bf16x8*>(
        reinterpret_cast<const char*>(base) + row * 128 + (kb ^ ((row & 7) << 4)));
}

// padded-LDS P strip (LDT=72)
#define LDT 72

// ---------------- m97-style GEMM: C[M][N] = A[M][K] @ B[N][K]^T + bias ----------------
template <int WN, int OUT_F32>
__global__ __launch_bounds__(256) void gemm_glds(
    const bf16* __restrict__ A, const bf16* __restrict__ Bm,
    const float* __restrict__ b0, const float* __restrict__ b1, const float* __restrict__ b2,
    float s0, void* __restrict__ Cv, int M, int N, int K)
{
    __shared__ __align__(16) bf16 As[128 * 64];
    __shared__ __align__(16) bf16 Bs[WN * 32 * 64];

    const int BN = WN * 32;
    const int nbn = N / BN;
    const int wrk = (blockIdx.x & 7) * ((int)gridDim.x >> 3) + (blockIdx.x >> 3);
    const int bm = wrk / nbn, bn = wrk % nbn;
    const int m0 = bm << 7, n0 = bn * BN;
    const int tid = threadIdx.x, lane = tid & 63, wid = tid >> 6;
    const int wr = wid >> 1, wc = wid & 1;
    const int lq = lane & 15, g = lane >> 4;

    f32x4 acc[4][WN];
    #pragma unroll
    for (int m = 0; m < 4; ++m)
        #pragma unroll
        for (int n = 0; n < WN; ++n)
            acc[m][n] = (f32x4){0.f, 0.f, 0.f, 0.f};

    for (int kt = 0; kt < K; kt += 64) {
        #pragma unroll
        for (int i = 0; i < 4; ++i) {
            int rb = wid * 32 + i * 8;
            gload16(&A[(size_t)(m0 + rb + (lane >> 3)) * K + kt + ((lane & 7) << 3)],
                    &As[rb * 64]);
        }
        #pragma unroll
        for (int i = 0; i < WN; ++i) {
            int rb = wid * (WN * 8) + i * 8;
            gload16(&Bm[(size_t)(n0 + rb + (lane >> 3)) * K + kt + ((lane & 7) << 3)],
                    &Bs[rb * 64]);
        }
        __syncthreads();

        bf16x8 af[4][2], bfr[WN][2];
        #pragma unroll
        for (int m = 0; m < 4; ++m)
            #pragma unroll
            for (int h2 = 0; h2 < 2; ++h2)
                af[m][h2] = fragswz(As, wr * 64 + m * 16 + lq, h2 * 64 + g * 16);
        #pragma unroll
        for (int n = 0; n < WN; ++n)
            #pragma unroll
            for (int h2 = 0; h2 < 2; ++h2)
                bfr[n][h2] = fragswz(Bs, wc * (WN * 16) + n * 16 + lq, h2 * 64 + g * 16);

        #pragma unroll
        for (int m = 0; m < 4; ++m)
            #pragma unroll
            for (int n = 0; n < WN; ++n)
                #pragma unroll
                for (int h2 = 0; h2 < 2; ++h2)
                    acc[m][n] = __builtin_amdgcn_mfma_f32_16x16x32_bf16(
                        af[m][h2], bfr[n][h2], acc[m][n], 0, 0, 0);
        __syncthreads();
    }

    const int seg = n0 >> 10;
    const float* bp = (seg == 0) ? b0 : ((seg == 1) ? b1 : b2);
    const float bsc = (seg == 0) ? s0 : 1.f;

    #pragma unroll
    for (int m = 0; m < 4; ++m) {
        #pragma unroll
        for (int n = 0; n < WN; ++n) {
            int rbase = m0 + wr * 64 + m * 16 + (g << 2);
            int col = n0 + wc * (WN * 16) + n * 16 + lq;
            float bv = bp[col - (seg << 10)] * bsc;
            #pragma unroll
            for (int r = 0; r < 4; ++r) {
                float v = acc[m][n][r] + bv;
                if (OUT_F32)
                    ((float*)Cv)[(size_t)(rbase + r) * N + col] = v;
                else
                    ((bf16*)Cv)[(size_t)(rbase + r) * N + col] = (bf16)v;
            }
        }
    }
}

// ---------------- fused decay-masked attention: k-split wave pairs -----------------
// 1024 blocks = (b, h, qblk64); 8 waves = 4 q-groups x 2 k-halves; each wave does
// 16 q-rows x 32 keys per tile (half the chain of R14). 3 blocks/CU = 24 waves/CU.
// kh-pair partial O/l combined once at the end via LDS (no-max softmax => additive).
struct KV { bf16x8 a, b; };

__device__ __forceinline__ void issue_kv(KV& r, const bf16* qkv, int brow,
                                         int koff, int voff, int tid) {
    if (tid < 256) {            // K role: rows rK, rK+32, chunk o
        const int rK = tid >> 3, o8 = (tid & 7) << 3;
        r.a = *reinterpret_cast<const bf16x8*>(&qkv[(size_t)(brow + rK) * 3072 + koff + o8]);
        r.b = *reinterpret_cast<const bf16x8*>(&qkv[(size_t)(brow + rK + 32) * 3072 + koff + o8]);
    } else {                    // V role: rows 2kp, 2kp+1, octet o
        const int t2 = tid - 256;
        const int kp = t2 >> 3, o8 = (t2 & 7) << 3;
        r.a = *reinterpret_cast<const bf16x8*>(&qkv[(size_t)(brow + 2 * kp) * 3072 + voff + o8]);
        r.b = *reinterpret_cast<const bf16x8*>(&qkv[(size_t)(brow + 2 * kp + 1) * 3072 + voff + o8]);
    }
}

__device__ __forceinline__ void write_kv(const KV& r, bf16* Kb, bf16* Vb, int tid) {
    if (tid < 256) {
        // K: [64][64] chunk-swizzled ((rK+32)&7 == rK&7)
        const int rK = tid >> 3, o = tid & 7;
        char* kb = reinterpret_cast<char*>(Kb);
        int kx = (o << 4) ^ ((rK & 7) << 4);
        *reinterpret_cast<bf16x8*>(kb + rK * 128 + kx) = r.a;
        *reinterpret_cast<bf16x8*>(kb + (rK + 32) * 128 + kx) = r.b;
    } else {
        // V^T: 144-stride, packed u32 of k-columns (2kp, 2kp+1)
        const int t2 = tid - 256;
        const int kp = t2 >> 3, o = t2 & 7;
        const u16x8 v0 = *reinterpret_cast<const u16x8*>(&r.a);
        const u16x8 v1 = *reinterpret_cast<const u16x8*>(&r.b);
        char* vb = reinterpret_cast<char*>(Vb);
        #pragma unroll
        for (int j = 0; j < 8; ++j) {
            int d = (o << 3) + j;
            int byteo = (d * 144 + kp * 4) ^ (o << 4);
            unsigned int w = (unsigned int)v0[j] | ((unsigned int)v1[j] << 16);
            *reinterpret_cast<unsigned int*>(vb + byteo) = w;
        }
    }
}

__global__ __launch_bounds__(512, 6) void attn_kernel(
    const bf16* __restrict__ qkv, const float* __restrict__ mask, bf16* __restrict__ Og)
{
    __shared__ __align__(16) bf16 Kbuf[2][64 * 64];   // 16 KB
    __shared__ __align__(16) bf16 Vbuf[2][64 * LDT];  // 18.4 KB
    __shared__ __align__(16) bf16 Ps[8][16 * LDT];    // 18.4 KB -> 52.75 KB, 3 blocks/CU

    // bid = xcd + 8*slot; slot = pg_local*4 + b  (4 b-siblings adjacent, same XCD)
    const int bid = blockIdx.x;
    const int xcd = bid & 7, slot = bid >> 3;
    const int b = slot & 3;
    const int pg = xcd * 32 + (slot >> 2);   // 0..255 = (h, qblk64)
    const int h = pg >> 4, qblk = pg & 15;

    const int tid = threadIdx.x, lane = tid & 63, wid = tid >> 6;
    const int kh = wid >> 2, qw = wid & 3;   // k-half role, q-group
    const int lq = lane & 15, g = lane >> 4;
    const int q = (qblk << 6) + qw * 16 + lq;
    const int brow = b * SEQ;
    const int koff = 1024 + h * HEADDIM, voff = 2048 + h * HEADDIM, qoff = h * HEADDIM;
    const float* mh = mask + (size_t)h * SEQ * SEQ + (size_t)q * SEQ + kh * 32;

    // Q fragments (pre-scaled by QSCALE via wq); full d=64 (QK contraction is over d)
    bf16x8 aq[2];
    #pragma unroll
    for (int h2 = 0; h2 < 2; ++h2)
        aq[h2] = *reinterpret_cast<const bf16x8*>(
            &qkv[(size_t)(brow + q) * 3072 + qoff + h2 * 32 + g * 8]);

    f32x4 lacc = {};
    f32x4 oacc[4] = {};

    // prologue
    KV s;
    issue_kv(s, qkv, brow, koff, voff, tid);
    write_kv(s, Kbuf[0], Vbuf[0], tid);
    issue_kv(s, qkv, brow + 64, koff, voff, tid);
    float4 mcur[2], mnxt[2];
    #pragma unroll
    for (int c = 0; c < 2; ++c)
        mcur[c] = *reinterpret_cast<const float4*>(&mh[c * 16 + (g << 2)]);
    __syncthreads();

    for (int t = 0; t < 16; ++t) {
        int pp = t & 1, np = pp ^ 1;
        if (t < 15) write_kv(s, Kbuf[np], Vbuf[np], tid);      // tile t+1 -> np
        if (t < 14) issue_kv(s, qkv, brow + (t + 2) * 64, koff, voff, tid);
        if (t < 15)
            #pragma unroll
            for (int c = 0; c < 2; ++c)
                mnxt[c] = *reinterpret_cast<const float4*>(&mh[(t + 1) * 64 + c * 16 + (g << 2)]);

        // ---- compute: this wave's 16 q-rows x its 32-k half ----
        {
            const bf16* Kb = Kbuf[pp];
            const char* vb = reinterpret_cast<const char*>(Vbuf[pp]);
            bf16* Psw = Ps[wid];
            f32x4 sacc[2];
            #pragma unroll
            for (int c = 0; c < 2; ++c) sacc[c] = (f32x4){0.f, 0.f, 0.f, 0.f};
            #pragma unroll
            for (int c = 0; c < 2; ++c)
                #pragma unroll
                for (int h2 = 0; h2 < 2; ++h2)
                    sacc[c] = __builtin_amdgcn_mfma_f32_16x16x32_bf16(
                        fragswz(Kb, (2 * kh + c) * 16 + lq, h2 * 64 + g * 16),
                        aq[h2], sacc[c], 0, 0, 0);

            #pragma unroll
            for (int c = 0; c < 2; ++c) {
                float p0 = __builtin_exp2f(sacc[c][0] * mcur[c].x);
                float p1 = __builtin_exp2f(sacc[c][1] * mcur[c].y);
                float p2 = __builtin_exp2f(sacc[c][2] * mcur[c].z);
                float p3 = __builtin_exp2f(sacc[c][3] * mcur[c].w);
                lacc[0] += p0; lacc[1] += p1; lacc[2] += p2; lacc[3] += p3;
                bf16x4 pbv;
                pbv[0] = (bf16)p0; pbv[1] = (bf16)p1; pbv[2] = (bf16)p2; pbv[3] = (bf16)p3;
                *reinterpret_cast<bf16x4*>(&Psw[lq * LDT + c * 16 + (g << 2)]) = pbv;
            }

            // PV over this wave's 32-k window (same-wave DS ordering is in-order)
            bf16x8 pf = *reinterpret_cast<const bf16x8*>(&Psw[lq * LDT + g * 8]);
            #pragma unroll
            for (int ot = 0; ot < 4; ++ot) {
                int d = ot * 16 + lq;
                int byteo = (d * 144 + (kh * 32 + g * 8) * 2) ^ (((d >> 3) & 7) << 4);
                bf16x8 vf = *reinterpret_cast<const bf16x8*>(vb + byteo);
                oacc[ot] = __builtin_amdgcn_mfma_f32_16x16x32_bf16(vf, pf, oacc[ot], 0, 0, 0);
            }
        }

        if (t < 15)
            #pragma unroll
            for (int c = 0; c < 2; ++c) mcur[c] = mnxt[c];
        __syncthreads();
    }

    // l: reduce over the 4 lane-groups within the wave
    float lsum = lacc[0] + lacc[1] + lacc[2] + lacc[3];
    lsum += __shfl_xor(lsum, 16, 64);
    lsum += __shfl_xor(lsum, 32, 64);

    // combine the kh pair via LDS (Kbuf/Vbuf free after the loop's final barrier)
    f32x4* cO = reinterpret_cast<f32x4*>(Vbuf);   // [ot][qw*64+lane], 16 KB
    float* cl = reinterpret_cast<float*>(Kbuf);   // [qw*64+lane], 1 KB
    if (kh == 1) {
        #pragma unroll
        for (int ot = 0; ot < 4; ++ot)
            cO[ot * 256 + qw * 64 + lane] = oacc[ot];
        cl[qw * 64 + lane] = lsum;
    }
    __syncthreads();
    if (kh == 0) {
        float inv = 1.f / (lsum + cl[qw * 64 + lane]);
        #pragma unroll
        for (int ot = 0; ot < 4; ++ot) {
            f32x4 o2 = cO[ot * 256 + qw * 64 + lane];
            bf16x4 o;
            o[0] = (bf16)((oacc[ot][0] + o2[0]) * inv);
            o[1] = (bf16)((oacc[ot][1] + o2[1]) * inv);
            o[2] = (bf16)((oacc[ot][2] + o2[2]) * inv);
            o[3] = (bf16)((oacc[ot][3] + o2[3]) * inv);
            int lcol = ot * 16 + (g << 2);
            int chunk = (lcol >> 3) ^ (q & 7);
            int col = h * HEADDIM + (chunk << 3) + (lcol & 7);
            *reinterpret_cast<bf16x4*>(&Og[(size_t)(brow + q) * DIMSZ + col]) = o;
        }
    }
}

extern "C" void kernel_launch(void* const* d_in, const int* in_sizes, int n_in,
                              void* d_out, int out_size, void* d_ws, size_t ws_size,
                              hipStream_t stream) {
    const float* x    = (const float*)d_in[0];
    const float* mask = (const float*)d_in[1];
    const float* wq   = (const float*)d_in[2];
    const float* bq   = (const float*)d_in[3];
    const float* wk   = (const float*)d_in[4];
    const float* bk   = (const float*)d_in[5];
    const float* wv   = (const float*)d_in[6];
    const float* bv   = (const float*)d_in[7];
    const float* wo   = (const float*)d_in[8];
    const float* bo   = (const float*)d_in[9];
    float* out = (float*)d_out;

    char* ws = (char*)d_ws;
    bf16* xb    = (bf16*)ws; ws += (size_t)MTOK * DIMSZ * 2;         // 8 MB
    bf16* wqkvb = (bf16*)ws; ws += (size_t)3 * DIMSZ * DIMSZ * 2;    // 6 MB
    bf16* wob   = (bf16*)ws; ws += (size_t)DIMSZ * DIMSZ * 2;        // 2 MB
    bf16* qkv   = (bf16*)ws; ws += (size_t)MTOK * 3 * DIMSZ * 2;     // 24 MB
    bf16* aob   = (bf16*)ws; ws += (size_t)MTOK * DIMSZ * 2;         // 8 MB -> 48 MB

    // single conversion launch (x + all four weights)
    cvt_all<<<(2 * 1048576) / 256, 256, 0, stream>>>(
        (const float4*)x, (const float4*)wq, (const float4*)wk,
        (const float4*)wv, (const float4*)wo, xb, wqkvb, wob);

    // fused QKV projection: [4096,1024] @ [3072,1024]^T -> [4096,3072] (linear bf16)
    gemm_glds<4, 0><<<(MTOK / 128) * (3 * DIMSZ / 128), 256, 0, stream>>>(
        xb, wqkvb, bq, bk, bv, QSCALE, qkv, MTOK, 3 * DIMSZ, DIMSZ);

    // fused attention -> aob (bf16, chunk-swizzled for the final GEMM)
    attn_kernel<<<1024, 512, 0, stream>>>(qkv, mask, aob);

    // output projection: [4096,1024] @ [1024,1024]^T -> [4096,1024] fp32
    gemm_glds<2, 1><<<(MTOK / 128) * (DIMSZ / 64), 256, 0, stream>>>(
        aob, wob, bo, bo, bo, 1.f, out, MTOK, DIMSZ, DIMSZ);
}

// Round 16
// 107.398 us; speedup vs baseline: 1.0464x; 1.0464x over previous
//
#include <hip/hip_runtime.h>
#include <hip/hip_bf16.h>
#include <math.h>

typedef __bf16 bf16;
typedef __bf16 bf16x8 __attribute__((ext_vector_type(8)));
typedef __bf16 bf16x4 __attribute__((ext_vector_type(4)));
typedef float f32x4 __attribute__((ext_vector_type(4)));
typedef unsigned short u16;
typedef u16 u16x8 __attribute__((ext_vector_type(8)));

#define SEQ 1024
#define DIMSZ 1024
#define NHEADS 16
#define HEADDIM 64
#define BATCH 4
#define MTOK (BATCH * SEQ)

// q-scale: 1/sqrt(64) * log2(e)  (log2e folded so softmax uses raw exp2)
#define QSCALE 0.180336880f

// ---------------- async global->LDS (16B per lane, linear dest) ----------------
typedef __attribute__((address_space(1))) const unsigned char gas_u8;
typedef __attribute__((address_space(3))) unsigned char las_u8;
__device__ __forceinline__ void gload16(const void* g, void* l) {
    __builtin_amdgcn_global_load_lds((const gas_u8*)g, (las_u8*)l, 16, 0, 0);
}

// ---------------- fp32 -> bf16 conversion with baked chunk-swizzle ----------------
// dst element (row, col) stored at chunk ^= (row&7) within each 64-col group
__device__ __forceinline__ void cvt_store(const float4 v, bf16* dst, int e0, float scale) {
    int row = e0 >> 10, col = e0 & 1023;
    int col2 = (col & ~63) | (col & 7) | (((((col >> 3) & 7) ^ (row & 7))) << 3);
    bf16x4 o;
    o[0] = (bf16)(v.x * scale);
    o[1] = (bf16)(v.y * scale);
    o[2] = (bf16)(v.z * scale);
    o[3] = (bf16)(v.w * scale);
    *reinterpret_cast<bf16x4*>(&dst[(size_t)row * 1024 + col2]) = o;
}

// single merged conversion launch: x -> xb; wq(*QSCALE),wk,wv -> wqkvb; wo -> wob
__global__ void cvt_all(const float4* __restrict__ x,
                        const float4* __restrict__ wq, const float4* __restrict__ wk,
                        const float4* __restrict__ wv, const float4* __restrict__ wo,
                        bf16* __restrict__ xb, bf16* __restrict__ wqkvb,
                        bf16* __restrict__ wob) {
    int i = blockIdx.x * blockDim.x + threadIdx.x;   // 0 .. 2*1048576-1
    if (i < 1048576) {
        cvt_store(x[i], xb, i << 2, 1.f);
    } else {
        int li = i - 1048576;
        int mat = li >> 18, lj = li & 262143;
        const float4* s = (mat == 0) ? wq : (mat == 1) ? wk : (mat == 2) ? wv : wo;
        bf16* d = (mat < 3) ? (wqkvb + (size_t)mat * 1024 * 1024) : wob;
        cvt_store(s[lj], d, lj << 2, (mat == 0) ? QSCALE : 1.f);
    }
}

// swizzled LDS fragment read from linear [rows][64] bf16 tile (128B rows)
__device__ __forceinline__ bf16x8 fragswz(const bf16* base, int row, int kb) {
    return *reinterpret_cast<const bf16x8*>(
        reinterpret_cast<const char*>(base) + row * 128 + (kb ^ ((row & 7) << 4)));
}

// padded-LDS P strip (LDT=72)
#define LDT 72

// ---------------- m97-style GEMM: C[M][N] = A[M][K] @ B[N][K]^T + bias ----------------
template <int WN, int OUT_F32>
__global__ __launch_bounds__(256) void gemm_glds(
    const bf16* __restrict__ A, const bf16* __restrict__ Bm,
    const float* __restrict__ b0, const float* __restrict__ b1, const float* __restrict__ b2,
    float s0, void* __restrict__ Cv, int M, int N, int K)
{
    __shared__ __align__(16) bf16 As[128 * 64];
    __shared__ __align__(16) bf16 Bs[WN * 32 * 64];

    const int BN = WN * 32;
    const int nbn = N / BN;
    const int wrk = (blockIdx.x & 7) * ((int)gridDim.x >> 3) + (blockIdx.x >> 3);
    const int bm = wrk / nbn, bn = wrk % nbn;
    const int m0 = bm << 7, n0 = bn * BN;
    const int tid = threadIdx.x, lane = tid & 63, wid = tid >> 6;
    const int wr = wid >> 1, wc = wid & 1;
    const int lq = lane & 15, g = lane >> 4;

    f32x4 acc[4][WN];
    #pragma unroll
    for (int m = 0; m < 4; ++m)
        #pragma unroll
        for (int n = 0; n < WN; ++n)
            acc[m][n] = (f32x4){0.f, 0.f, 0.f, 0.f};

    for (int kt = 0; kt < K; kt += 64) {
        #pragma unroll
        for (int i = 0; i < 4; ++i) {
            int rb = wid * 32 + i * 8;
            gload16(&A[(size_t)(m0 + rb + (lane >> 3)) * K + kt + ((lane & 7) << 3)],
                    &As[rb * 64]);
        }
        #pragma unroll
        for (int i = 0; i < WN; ++i) {
            int rb = wid * (WN * 8) + i * 8;
            gload16(&Bm[(size_t)(n0 + rb + (lane >> 3)) * K + kt + ((lane & 7) << 3)],
                    &Bs[rb * 64]);
        }
        __syncthreads();

        bf16x8 af[4][2], bfr[WN][2];
        #pragma unroll
        for (int m = 0; m < 4; ++m)
            #pragma unroll
            for (int h2 = 0; h2 < 2; ++h2)
                af[m][h2] = fragswz(As, wr * 64 + m * 16 + lq, h2 * 64 + g * 16);
        #pragma unroll
        for (int n = 0; n < WN; ++n)
            #pragma unroll
            for (int h2 = 0; h2 < 2; ++h2)
                bfr[n][h2] = fragswz(Bs, wc * (WN * 16) + n * 16 + lq, h2 * 64 + g * 16);

        #pragma unroll
        for (int m = 0; m < 4; ++m)
            #pragma unroll
            for (int n = 0; n < WN; ++n)
                #pragma unroll
                for (int h2 = 0; h2 < 2; ++h2)
                    acc[m][n] = __builtin_amdgcn_mfma_f32_16x16x32_bf16(
                        af[m][h2], bfr[n][h2], acc[m][n], 0, 0, 0);
        __syncthreads();
    }

    const int seg = n0 >> 10;
    const float* bp = (seg == 0) ? b0 : ((seg == 1) ? b1 : b2);
    const float bsc = (seg == 0) ? s0 : 1.f;

    #pragma unroll
    for (int m = 0; m < 4; ++m) {
        #pragma unroll
        for (int n = 0; n < WN; ++n) {
            int rbase = m0 + wr * 64 + m * 16 + (g << 2);
            int col = n0 + wc * (WN * 16) + n * 16 + lq;
            float bv = bp[col - (seg << 10)] * bsc;
            #pragma unroll
            for (int r = 0; r < 4; ++r) {
                float v = acc[m][n][r] + bv;
                if (OUT_F32)
                    ((float*)Cv)[(size_t)(rbase + r) * N + col] = v;
                else
                    ((bf16*)Cv)[(size_t)(rbase + r) * N + col] = (bf16)v;
            }
        }
    }
}

// ---------------- fused decay-masked attention: 8-wave blocks, gload-K ----------
// 512 blocks = (b, h, qblk128); 8 waves x 16 q-rows = 128 q per block.
// K staged via global_load_lds (waves 0-3): per-lane pre-swizzled GLOBAL chunk,
// linear LDS dest -> reproduces the [64][64] chunk-swizzled layout with zero
// staging VALU/registers. V (waves 4-7) reg-staged transpose (144-stride).
// One barrier per k-tile (16 tiles). No-max softmax.
struct VRg { bf16x8 a, b; };

__device__ __forceinline__ void issue_v(VRg& r, const bf16* qkv, int brow,
                                        int voff, int t2) {
    const int kp = t2 >> 3, o8 = (t2 & 7) << 3;
    r.a = *reinterpret_cast<const bf16x8*>(&qkv[(size_t)(brow + 2 * kp) * 3072 + voff + o8]);
    r.b = *reinterpret_cast<const bf16x8*>(&qkv[(size_t)(brow + 2 * kp + 1) * 3072 + voff + o8]);
}

__device__ __forceinline__ void write_v(const VRg& r, bf16* Vb, int t2) {
    // V^T: 144-stride, packed u32 of k-columns (2kp, 2kp+1)
    const int kp = t2 >> 3, o = t2 & 7;
    const u16x8 v0 = *reinterpret_cast<const u16x8*>(&r.a);
    const u16x8 v1 = *reinterpret_cast<const u16x8*>(&r.b);
    char* vb = reinterpret_cast<char*>(Vb);
    #pragma unroll
    for (int j = 0; j < 8; ++j) {
        int d = (o << 3) + j;
        int byteo = (d * 144 + kp * 4) ^ (o << 4);
        unsigned int w = (unsigned int)v0[j] | ((unsigned int)v1[j] << 16);
        *reinterpret_cast<unsigned int*>(vb + byteo) = w;
    }
}

// K tile staging via global_load_lds. Wave w (0..3) covers rows
// [8w, 8w+8) and [8w+32, 8w+40). Lane l -> row 8w+(l>>3), LDS slot l&7;
// global source chunk (l&7)^(l>>3) so slot s of row r holds chunk s^(r&7),
// exactly what fragswz expects.
__device__ __forceinline__ void kstage_glds(const bf16* qkv, int brow, int koff,
                                            bf16* Kb, int wid, int lane) {
    const int lr = lane >> 3;
    const int chunk = (lane & 7) ^ lr;
    const int r0 = wid * 8;
    gload16(&qkv[(size_t)(brow + r0 + lr) * 3072 + koff + (chunk << 3)],
            &Kb[r0 * 64]);
    gload16(&qkv[(size_t)(brow + r0 + 32 + lr) * 3072 + koff + (chunk << 3)],
            &Kb[(r0 + 32) * 64]);
}

// No-max softmax: |s| bounded, mask in [0,1] -> exp2 safe without max
// subtraction; row-sum accumulated per-lane, reduced once in epilogue.
__device__ __forceinline__ void compute_stage(
    const bf16* Kb, const bf16* Vb, bf16* Psw,
    const float4 (&mreg)[4], const bf16x8 (&aqb)[2],
    f32x4& lacc, f32x4 (&oacc)[4], int lane)
{
    const int lq = lane & 15, g = lane >> 4;
    f32x4 sacc[4];
    #pragma unroll
    for (int ct = 0; ct < 4; ++ct) sacc[ct] = (f32x4){0.f, 0.f, 0.f, 0.f};
    #pragma unroll
    for (int ct = 0; ct < 4; ++ct)
        #pragma unroll
        for (int h2 = 0; h2 < 2; ++h2)
            sacc[ct] = __builtin_amdgcn_mfma_f32_16x16x32_bf16(
                fragswz(Kb, ct * 16 + lq, h2 * 64 + g * 16), aqb[h2], sacc[ct], 0, 0, 0);

    // p = exp2(s * mask); accumulate row-sum; pack P
    #pragma unroll
    for (int ct = 0; ct < 4; ++ct) {
        float p0 = __builtin_exp2f(sacc[ct][0] * mreg[ct].x);
        float p1 = __builtin_exp2f(sacc[ct][1] * mreg[ct].y);
        float p2 = __builtin_exp2f(sacc[ct][2] * mreg[ct].z);
        float p3 = __builtin_exp2f(sacc[ct][3] * mreg[ct].w);
        lacc[0] += p0; lacc[1] += p1; lacc[2] += p2; lacc[3] += p3;
        bf16x4 pbv;
        pbv[0] = (bf16)p0; pbv[1] = (bf16)p1; pbv[2] = (bf16)p2; pbv[3] = (bf16)p3;
        *reinterpret_cast<bf16x4*>(&Psw[lq * LDT + ct * 16 + (g << 2)]) = pbv;
    }

    // O^T += mfma(V^T rows d, P rows q)   (same-wave DS ordering is in-order)
    const char* vb = reinterpret_cast<const char*>(Vb);
    #pragma unroll
    for (int ot = 0; ot < 4; ++ot) {
        #pragma unroll
        for (int h2 = 0; h2 < 2; ++h2) {
            int d = ot * 16 + lq;
            int byteo = (d * 144 + (h2 * 32 + g * 8) * 2) ^ (((d >> 3) & 7) << 4);
            bf16x8 vf = *reinterpret_cast<const bf16x8*>(vb + byteo);
            bf16x8 pf = *reinterpret_cast<const bf16x8*>(&Psw[lq * LDT + h2 * 32 + g * 8]);
            oacc[ot] = __builtin_amdgcn_mfma_f32_16x16x32_bf16(vf, pf, oacc[ot], 0, 0, 0);
        }
    }
}

__global__ __launch_bounds__(512, 4) void attn_kernel(
    const bf16* __restrict__ qkv, const float* __restrict__ mask, bf16* __restrict__ Og)
{
    __shared__ __align__(16) bf16 Kbuf[2][64 * 64];   // 8 KB x2
    __shared__ __align__(16) bf16 Vbuf[2][64 * LDT];  // 9.2 KB x2
    __shared__ __align__(16) bf16 Ps[8][16 * LDT];    // 18.4 KB -> 52 KB total

    // bid = xcd + 8*slot; slot = pg_local*4 + b  (4 b-siblings adjacent, same XCD)
    const int bid = blockIdx.x;
    const int xcd = bid & 7, slot = bid >> 3;
    const int b = slot & 3;
    const int pg = xcd * 16 + (slot >> 2);   // 0..127 = (h, qblk128)
    const int h = pg >> 3, qblk = pg & 7;

    const int tid = threadIdx.x, lane = tid & 63, wid = tid >> 6;
    const int lq = lane & 15, g = lane >> 4;
    const int q = (qblk << 7) + wid * 16 + lq;
    const int brow = b * SEQ;
    const int koff = 1024 + h * HEADDIM, voff = 2048 + h * HEADDIM, qoff = h * HEADDIM;
    const float* mh = mask + (size_t)h * SEQ * SEQ + (size_t)q * SEQ;
    const bool kRole = (wid < 4);
    const int t2 = tid & 255;   // V-role thread index (tid-256 when wid>=4)

    // Q fragments (pre-scaled by QSCALE via wq)
    bf16x8 aq[2];
    #pragma unroll
    for (int h2 = 0; h2 < 2; ++h2)
        aq[h2] = *reinterpret_cast<const bf16x8*>(
            &qkv[(size_t)(brow + q) * 3072 + qoff + h2 * 32 + g * 8]);

    f32x4 lacc = {};
    f32x4 oacc[4] = {};

    // prologue: K tile0 via gload; V tile0 reg-staged; V tile1 loads in regs
    VRg s;
    if (kRole) {
        kstage_glds(qkv, brow, koff, Kbuf[0], wid, lane);
    } else {
        issue_v(s, qkv, brow, voff, t2);
        write_v(s, Vbuf[0], t2);
        issue_v(s, qkv, brow + 64, voff, t2);
    }
    float4 mcur[4], mnxt[4];
    #pragma unroll
    for (int ct = 0; ct < 4; ++ct)
        mcur[ct] = *reinterpret_cast<const float4*>(&mh[ct * 16 + (g << 2)]);
    __syncthreads();

    for (int t = 0; t < 16; ++t) {
        int pp = t & 1, np = pp ^ 1;
        if (t < 15) {
            if (kRole) kstage_glds(qkv, brow + (t + 1) * 64, koff, Kbuf[np], wid, lane);
            else       write_v(s, Vbuf[np], t2);            // tile t+1 -> np
        }
        if (t < 14 && !kRole) issue_v(s, qkv, brow + (t + 2) * 64, voff, t2);
        // mask(t+1) issued BEFORE compute so its latency hides under compute
        if (t < 15)
            #pragma unroll
            for (int ct = 0; ct < 4; ++ct)
                mnxt[ct] = *reinterpret_cast<const float4*>(&mh[(t + 1) * 64 + ct * 16 + (g << 2)]);
        compute_stage(Kbuf[pp], Vbuf[pp], Ps[wid], mcur, aq, lacc, oacc, lane);
        if (t < 15)
            #pragma unroll
            for (int ct = 0; ct < 4; ++ct) mcur[ct] = mnxt[ct];
        __syncthreads();
    }

    // epilogue: cross-lane l reduction, then O stores (chunk-swizzled for GEMM)
    float lsum = lacc[0] + lacc[1] + lacc[2] + lacc[3];
    lsum += __shfl_xor(lsum, 16, 64);
    lsum += __shfl_xor(lsum, 32, 64);
    float inv = 1.f / lsum;
    #pragma unroll
    for (int ot = 0; ot < 4; ++ot) {
        bf16x4 o;
        o[0] = (bf16)(oacc[ot][0] * inv);
        o[1] = (bf16)(oacc[ot][1] * inv);
        o[2] = (bf16)(oacc[ot][2] * inv);
        o[3] = (bf16)(oacc[ot][3] * inv);
        int lcol = ot * 16 + (g << 2);
        int chunk = (lcol >> 3) ^ (q & 7);
        int col = h * HEADDIM + (chunk << 3) + (lcol & 7);
        *reinterpret_cast<bf16x4*>(&Og[(size_t)(brow + q) * DIMSZ + col]) = o;
    }
}

extern "C" void kernel_launch(void* const* d_in, const int* in_sizes, int n_in,
                              void* d_out, int out_size, void* d_ws, size_t ws_size,
                              hipStream_t stream) {
    const float* x    = (const float*)d_in[0];
    const float* mask = (const float*)d_in[1];
    const float* wq   = (const float*)d_in[2];
    const float* bq   = (const float*)d_in[3];
    const float* wk   = (const float*)d_in[4];
    const float* bk   = (const float*)d_in[5];
    const float* wv   = (const float*)d_in[6];
    const float* bv   = (const float*)d_in[7];
    const float* wo   = (const float*)d_in[8];
    const float* bo   = (const float*)d_in[9];
    float* out = (float*)d_out;

    char* ws = (char*)d_ws;
    bf16* xb    = (bf16*)ws; ws += (size_t)MTOK * DIMSZ * 2;         // 8 MB
    bf16* wqkvb = (bf16*)ws; ws += (size_t)3 * DIMSZ * DIMSZ * 2;    // 6 MB
    bf16* wob   = (bf16*)ws; ws += (size_t)DIMSZ * DIMSZ * 2;        // 2 MB
    bf16* qkv   = (bf16*)ws; ws += (size_t)MTOK * 3 * DIMSZ * 2;     // 24 MB
    bf16* aob   = (bf16*)ws; ws += (size_t)MTOK * DIMSZ * 2;         // 8 MB -> 48 MB

    // single conversion launch (x + all four weights)
    cvt_all<<<(2 * 1048576) / 256, 256, 0, stream>>>(
        (const float4*)x, (const float4*)wq, (const float4*)wk,
        (const float4*)wv, (const float4*)wo, xb, wqkvb, wob);

    // fused QKV projection: [4096,1024] @ [3072,1024]^T -> [4096,3072] (linear bf16)
    gemm_glds<4, 0><<<(MTOK / 128) * (3 * DIMSZ / 128), 256, 0, stream>>>(
        xb, wqkvb, bq, bk, bv, QSCALE, qkv, MTOK, 3 * DIMSZ, DIMSZ);

    // fused attention -> aob (bf16, chunk-swizzled for the final GEMM)
    attn_kernel<<<512, 512, 0, stream>>>(qkv, mask, aob);

    // output projection: [4096,1024] @ [1024,1024]^T -> [4096,1024] fp32
    gemm_glds<2, 1><<<(MTOK / 128) * (DIMSZ / 64), 256, 0, stream>>>(
        aob, wob, bo, bo, bo, 1.f, out, MTOK, DIMSZ, DIMSZ);
}

// Round 17
// 105.537 us; speedup vs baseline: 1.0648x; 1.0176x over previous
//
#include <hip/hip_runtime.h>
#include <hip/hip_bf16.h>
#include <math.h>

typedef __bf16 bf16;
typedef __bf16 bf16x8 __attribute__((ext_vector_type(8)));
typedef __bf16 bf16x4 __attribute__((ext_vector_type(4)));
typedef float f32x4 __attribute__((ext_vector_type(4)));
typedef unsigned short u16;
typedef u16 u16x8 __attribute__((ext_vector_type(8)));

#define SEQ 1024
#define DIMSZ 1024
#define NHEADS 16
#define HEADDIM 64
#define BATCH 4
#define MTOK (BATCH * SEQ)

// q-scale: 1/sqrt(64) * log2(e)  (log2e folded so softmax uses raw exp2)
#define QSCALE 0.180336880f

// ---------------- async global->LDS (16B per lane, linear dest) ----------------
typedef __attribute__((address_space(1))) const unsigned char gas_u8;
typedef __attribute__((address_space(3))) unsigned char las_u8;
__device__ __forceinline__ void gload16(const void* g, void* l) {
    __builtin_amdgcn_global_load_lds((const gas_u8*)g, (las_u8*)l, 16, 0, 0);
}

// ---------------- fp32 -> bf16 conversion with baked chunk-swizzle ----------------
// dst element (row, col) stored at chunk ^= (row&7) within each 64-col group
__device__ __forceinline__ void cvt_store(const float4 v, bf16* dst, int e0, float scale) {
    int row = e0 >> 10, col = e0 & 1023;
    int col2 = (col & ~63) | (col & 7) | (((((col >> 3) & 7) ^ (row & 7))) << 3);
    bf16x4 o;
    o[0] = (bf16)(v.x * scale);
    o[1] = (bf16)(v.y * scale);
    o[2] = (bf16)(v.z * scale);
    o[3] = (bf16)(v.w * scale);
    *reinterpret_cast<bf16x4*>(&dst[(size_t)row * 1024 + col2]) = o;
}

// single merged conversion launch: x -> xb; wq(*QSCALE),wk,wv -> wqkvb; wo -> wob
__global__ void cvt_all(const float4* __restrict__ x,
                        const float4* __restrict__ wq, const float4* __restrict__ wk,
                        const float4* __restrict__ wv, const float4* __restrict__ wo,
                        bf16* __restrict__ xb, bf16* __restrict__ wqkvb,
                        bf16* __restrict__ wob) {
    int i = blockIdx.x * blockDim.x + threadIdx.x;   // 0 .. 2*1048576-1
    if (i < 1048576) {
        cvt_store(x[i], xb, i << 2, 1.f);
    } else {
        int li = i - 1048576;
        int mat = li >> 18, lj = li & 262143;
        const float4* s = (mat == 0) ? wq : (mat == 1) ? wk : (mat == 2) ? wv : wo;
        bf16* d = (mat < 3) ? (wqkvb + (size_t)mat * 1024 * 1024) : wob;
        cvt_store(s[lj], d, lj << 2, (mat == 0) ? QSCALE : 1.f);
    }
}

// swizzled LDS fragment read from linear [rows][64] bf16 tile (128B rows)
__device__ __forceinline__ bf16x8 fragswz(const bf16* base, int row, int kb) {
    return *reinterpret_cast<const bf16x8*>(
        reinterpret_cast<const char*>(base) + row * 128 + (kb ^ ((row & 7) << 4)));
}

// padded-LDS P strip (LDT=72)
#define LDT 72

// ---------------- m97-style GEMM: C[M][N] = A[M][K] @ B[N][K]^T + bias ----------------
template <int WN, int OUT_F32>
__global__ __launch_bounds__(256) void gemm_glds(
    const bf16* __restrict__ A, const bf16* __restrict__ Bm,
    const float* __restrict__ b0, const float* __restrict__ b1, const float* __restrict__ b2,
    float s0, void* __restrict__ Cv, int M, int N, int K)
{
    __shared__ __align__(16) bf16 As[128 * 64];
    __shared__ __align__(16) bf16 Bs[WN * 32 * 64];

    const int BN = WN * 32;
    const int nbn = N / BN;
    const int wrk = (blockIdx.x & 7) * ((int)gridDim.x >> 3) + (blockIdx.x >> 3);
    const int bm = wrk / nbn, bn = wrk % nbn;
    const int m0 = bm << 7, n0 = bn * BN;
    const int tid = threadIdx.x, lane = tid & 63, wid = tid >> 6;
    const int wr = wid >> 1, wc = wid & 1;
    const int lq = lane & 15, g = lane >> 4;

    f32x4 acc[4][WN];
    #pragma unroll
    for (int m = 0; m < 4; ++m)
        #pragma unroll
        for (int n = 0; n < WN; ++n)
            acc[m][n] = (f32x4){0.f, 0.f, 0.f, 0.f};

    for (int kt = 0; kt < K; kt += 64) {
        #pragma unroll
        for (int i = 0; i < 4; ++i) {
            int rb = wid * 32 + i * 8;
            gload16(&A[(size_t)(m0 + rb + (lane >> 3)) * K + kt + ((lane & 7) << 3)],
                    &As[rb * 64]);
        }
        #pragma unroll
        for (int i = 0; i < WN; ++i) {
            int rb = wid * (WN * 8) + i * 8;
            gload16(&Bm[(size_t)(n0 + rb + (lane >> 3)) * K + kt + ((lane & 7) << 3)],
                    &Bs[rb * 64]);
        }
        __syncthreads();

        bf16x8 af[4][2], bfr[WN][2];
        #pragma unroll
        for (int m = 0; m < 4; ++m)
            #pragma unroll
            for (int h2 = 0; h2 < 2; ++h2)
                af[m][h2] = fragswz(As, wr * 64 + m * 16 + lq, h2 * 64 + g * 16);
        #pragma unroll
        for (int n = 0; n < WN; ++n)
            #pragma unroll
            for (int h2 = 0; h2 < 2; ++h2)
                bfr[n][h2] = fragswz(Bs, wc * (WN * 16) + n * 16 + lq, h2 * 64 + g * 16);

        #pragma unroll
        for (int m = 0; m < 4; ++m)
            #pragma unroll
            for (int n = 0; n < WN; ++n)
                #pragma unroll
                for (int h2 = 0; h2 < 2; ++h2)
                    acc[m][n] = __builtin_amdgcn_mfma_f32_16x16x32_bf16(
                        af[m][h2], bfr[n][h2], acc[m][n], 0, 0, 0);
        __syncthreads();
    }

    const int seg = n0 >> 10;
    const float* bp = (seg == 0) ? b0 : ((seg == 1) ? b1 : b2);
    const float bsc = (seg == 0) ? s0 : 1.f;

    #pragma unroll
    for (int m = 0; m < 4; ++m) {
        #pragma unroll
        for (int n = 0; n < WN; ++n) {
            int rbase = m0 + wr * 64 + m * 16 + (g << 2);
            int col = n0 + wc * (WN * 16) + n * 16 + lq;
            float bv = bp[col - (seg << 10)] * bsc;
            #pragma unroll
            for (int r = 0; r < 4; ++r) {
                float v = acc[m][n][r] + bv;
                if (OUT_F32)
                    ((float*)Cv)[(size_t)(rbase + r) * N + col] = v;
                else
                    ((bf16*)Cv)[(size_t)(rbase + r) * N + col] = (bf16)v;
            }
        }
    }
}

// ---------------- fused decay-masked attention: 8-wave blocks, 16 waves/CU ----------
// 512 blocks = (b, h, qblk128); 8 waves x 16 q-rows = 128 q per block.
// K/V staged once per block per tile (waves 0-3 stage K, waves 4-7 stage V).
// One barrier per k-tile (16 tiles). No-max softmax.
// Mask loads issued BEFORE compute (dist-1 pipeline) so the barrier's
// vmcnt(0) drain doesn't expose their L3 latency.
struct KV { bf16x8 a, b; };

__device__ __forceinline__ void issue_kv(KV& r, const bf16* qkv, int brow,
                                         int koff, int voff, int tid) {
    if (tid < 256) {            // K role: rows rK, rK+32, chunk o
        const int rK = tid >> 3, o8 = (tid & 7) << 3;
        r.a = *reinterpret_cast<const bf16x8*>(&qkv[(size_t)(brow + rK) * 3072 + koff + o8]);
        r.b = *reinterpret_cast<const bf16x8*>(&qkv[(size_t)(brow + rK + 32) * 3072 + koff + o8]);
    } else {                    // V role: rows 2kp, 2kp+1, octet o
        const int t2 = tid - 256;
        const int kp = t2 >> 3, o8 = (t2 & 7) << 3;
        r.a = *reinterpret_cast<const bf16x8*>(&qkv[(size_t)(brow + 2 * kp) * 3072 + voff + o8]);
        r.b = *reinterpret_cast<const bf16x8*>(&qkv[(size_t)(brow + 2 * kp + 1) * 3072 + voff + o8]);
    }
}

__device__ __forceinline__ void write_kv(const KV& r, bf16* Kb, bf16* Vb, int tid) {
    if (tid < 256) {
        // K: [64][64] chunk-swizzled ((rK+32)&7 == rK&7)
        const int rK = tid >> 3, o = tid & 7;
        char* kb = reinterpret_cast<char*>(Kb);
        int kx = (o << 4) ^ ((rK & 7) << 4);
        *reinterpret_cast<bf16x8*>(kb + rK * 128 + kx) = r.a;
        *reinterpret_cast<bf16x8*>(kb + (rK + 32) * 128 + kx) = r.b;
    } else {
        // V^T: 144-stride, packed u32 of k-columns (2kp, 2kp+1)
        const int t2 = tid - 256;
        const int kp = t2 >> 3, o = t2 & 7;
        const u16x8 v0 = *reinterpret_cast<const u16x8*>(&r.a);
        const u16x8 v1 = *reinterpret_cast<const u16x8*>(&r.b);
        char* vb = reinterpret_cast<char*>(Vb);
        #pragma unroll
        for (int j = 0; j < 8; ++j) {
            int d = (o << 3) + j;
            int byteo = (d * 144 + kp * 4) ^ (o << 4);
            unsigned int w = (unsigned int)v0[j] | ((unsigned int)v1[j] << 16);
            *reinterpret_cast<unsigned int*>(vb + byteo) = w;
        }
    }
}

// No-max softmax: |s| bounded, mask in [0,1] -> exp2 safe without max
// subtraction; row-sum accumulated per-lane, reduced once in epilogue.
__device__ __forceinline__ void compute_stage(
    const bf16* Kb, const bf16* Vb, bf16* Psw,
    const float4 (&mreg)[4], const bf16x8 (&aqb)[2],
    f32x4& lacc, f32x4 (&oacc)[4], int lane)
{
    const int lq = lane & 15, g = lane >> 4;
    f32x4 sacc[4];
    #pragma unroll
    for (int ct = 0; ct < 4; ++ct) sacc[ct] = (f32x4){0.f, 0.f, 0.f, 0.f};
    #pragma unroll
    for (int ct = 0; ct < 4; ++ct)
        #pragma unroll
        for (int h2 = 0; h2 < 2; ++h2)
            sacc[ct] = __builtin_amdgcn_mfma_f32_16x16x32_bf16(
                fragswz(Kb, ct * 16 + lq, h2 * 64 + g * 16), aqb[h2], sacc[ct], 0, 0, 0);

    // p = exp2(s * mask); accumulate row-sum; pack P
    #pragma unroll
    for (int ct = 0; ct < 4; ++ct) {
        float p0 = __builtin_exp2f(sacc[ct][0] * mreg[ct].x);
        float p1 = __builtin_exp2f(sacc[ct][1] * mreg[ct].y);
        float p2 = __builtin_exp2f(sacc[ct][2] * mreg[ct].z);
        float p3 = __builtin_exp2f(sacc[ct][3] * mreg[ct].w);
        lacc[0] += p0; lacc[1] += p1; lacc[2] += p2; lacc[3] += p3;
        bf16x4 pbv;
        pbv[0] = (bf16)p0; pbv[1] = (bf16)p1; pbv[2] = (bf16)p2; pbv[3] = (bf16)p3;
        *reinterpret_cast<bf16x4*>(&Psw[lq * LDT + ct * 16 + (g << 2)]) = pbv;
    }

    // O^T += mfma(V^T rows d, P rows q)   (same-wave DS ordering is in-order)
    const char* vb = reinterpret_cast<const char*>(Vb);
    #pragma unroll
    for (int ot = 0; ot < 4; ++ot) {
        #pragma unroll
        for (int h2 = 0; h2 < 2; ++h2) {
            int d = ot * 16 + lq;
            int byteo = (d * 144 + (h2 * 32 + g * 8) * 2) ^ (((d >> 3) & 7) << 4);
            bf16x8 vf = *reinterpret_cast<const bf16x8*>(vb + byteo);
            bf16x8 pf = *reinterpret_cast<const bf16x8*>(&Psw[lq * LDT + h2 * 32 + g * 8]);
            oacc[ot] = __builtin_amdgcn_mfma_f32_16x16x32_bf16(vf, pf, oacc[ot], 0, 0, 0);
        }
    }
}

__global__ __launch_bounds__(512, 4) void attn_kernel(
    const bf16* __restrict__ qkv, const float* __restrict__ mask, bf16* __restrict__ Og)
{
    __shared__ __align__(16) bf16 Kbuf[2][64 * 64];   // 8 KB x2
    __shared__ __align__(16) bf16 Vbuf[2][64 * LDT];  // 9.2 KB x2
    __shared__ __align__(16) bf16 Ps[8][16 * LDT];    // 18.4 KB -> 52 KB total

    // bid = xcd + 8*slot; slot = pg_local*4 + b  (4 b-siblings adjacent, same XCD)
    const int bid = blockIdx.x;
    const int xcd = bid & 7, slot = bid >> 3;
    const int b = slot & 3;
    const int pg = xcd * 16 + (slot >> 2);   // 0..127 = (h, qblk128)
    const int h = pg >> 3, qblk = pg & 7;

    const int tid = threadIdx.x, lane = tid & 63, wid = tid >> 6;
    const int lq = lane & 15, g = lane >> 4;
    const int q = (qblk << 7) + wid * 16 + lq;
    const int brow = b * SEQ;
    const int koff = 1024 + h * HEADDIM, voff = 2048 + h * HEADDIM, qoff = h * HEADDIM;
    const float* mh = mask + (size_t)h * SEQ * SEQ + (size_t)q * SEQ;

    // Q fragments (pre-scaled by QSCALE via wq)
    bf16x8 aq[2];
    #pragma unroll
    for (int h2 = 0; h2 < 2; ++h2)
        aq[h2] = *reinterpret_cast<const bf16x8*>(
            &qkv[(size_t)(brow + q) * 3072 + qoff + h2 * 32 + g * 8]);

    f32x4 lacc = {};
    f32x4 oacc[4] = {};

    // prologue: tile0 -> buf0; tile1 loads in regs; mask tile 0 in regs
    KV s;
    issue_kv(s, qkv, brow, koff, voff, tid);
    write_kv(s, Kbuf[0], Vbuf[0], tid);
    issue_kv(s, qkv, brow + 64, koff, voff, tid);
    float4 mcur[4], mnxt[4];
    #pragma unroll
    for (int ct = 0; ct < 4; ++ct)
        mcur[ct] = *reinterpret_cast<const float4*>(&mh[ct * 16 + (g << 2)]);
    __syncthreads();

    for (int t = 0; t < 16; ++t) {
        int pp = t & 1, np = pp ^ 1;
        if (t < 15) write_kv(s, Kbuf[np], Vbuf[np], tid);      // tile t+1 -> np
        if (t < 14) issue_kv(s, qkv, brow + (t + 2) * 64, koff, voff, tid);
        // mask(t+1) issued BEFORE compute so its latency hides under compute
        // (the barrier's vmcnt(0) drain would otherwise expose it cold)
        if (t < 15)
            #pragma unroll
            for (int ct = 0; ct < 4; ++ct)
                mnxt[ct] = *reinterpret_cast<const float4*>(&mh[(t + 1) * 64 + ct * 16 + (g << 2)]);
        compute_stage(Kbuf[pp], Vbuf[pp], Ps[wid], mcur, aq, lacc, oacc, lane);
        if (t < 15)
            #pragma unroll
            for (int ct = 0; ct < 4; ++ct) mcur[ct] = mnxt[ct];
        __syncthreads();
    }

    // epilogue: cross-lane l reduction, then O stores (chunk-swizzled for GEMM)
    float lsum = lacc[0] + lacc[1] + lacc[2] + lacc[3];
    lsum += __shfl_xor(lsum, 16, 64);
    lsum += __shfl_xor(lsum, 32, 64);
    float inv = 1.f / lsum;
    #pragma unroll
    for (int ot = 0; ot < 4; ++ot) {
        bf16x4 o;
        o[0] = (bf16)(oacc[ot][0] * inv);
        o[1] = (bf16)(oacc[ot][1] * inv);
        o[2] = (bf16)(oacc[ot][2] * inv);
        o[3] = (bf16)(oacc[ot][3] * inv);
        int lcol = ot * 16 + (g << 2);
        int chunk = (lcol >> 3) ^ (q & 7);
        int col = h * HEADDIM + (chunk << 3) + (lcol & 7);
        *reinterpret_cast<bf16x4*>(&Og[(size_t)(brow + q) * DIMSZ + col]) = o;
    }
}

extern "C" void kernel_launch(void* const* d_in, const int* in_sizes, int n_in,
                              void* d_out, int out_size, void* d_ws, size_t ws_size,
                              hipStream_t stream) {
    const float* x    = (const float*)d_in[0];
    const float* mask = (const float*)d_in[1];
    const float* wq   = (const float*)d_in[2];
    const float* bq   = (const float*)d_in[3];
    const float* wk   = (const float*)d_in[4];
    const float* bk   = (const float*)d_in[5];
    const float* wv   = (const float*)d_in[6];
    const float* bv   = (const float*)d_in[7];
    const float* wo   = (const float*)d_in[8];
    const float* bo   = (const float*)d_in[9];
    float* out = (float*)d_out;

    char* ws = (char*)d_ws;
    bf16* xb    = (bf16*)ws; ws += (size_t)MTOK * DIMSZ * 2;         // 8 MB
    bf16* wqkvb = (bf16*)ws; ws += (size_t)3 * DIMSZ * DIMSZ * 2;    // 6 MB
    bf16* wob   = (bf16*)ws; ws += (size_t)DIMSZ * DIMSZ * 2;        // 2 MB
    bf16* qkv   = (bf16*)ws; ws += (size_t)MTOK * 3 * DIMSZ * 2;     // 24 MB
    bf16* aob   = (bf16*)ws; ws += (size_t)MTOK * DIMSZ * 2;         // 8 MB -> 48 MB

    // single conversion launch (x + all four weights)
    cvt_all<<<(2 * 1048576) / 256, 256, 0, stream>>>(
        (const float4*)x, (const float4*)wq, (const float4*)wk,
        (const float4*)wv, (const float4*)wo, xb, wqkvb, wob);

    // fused QKV projection: [4096,1024] @ [3072,1024]^T -> [4096,3072] (linear bf16)
    gemm_glds<4, 0><<<(MTOK / 128) * (3 * DIMSZ / 128), 256, 0, stream>>>(
        xb, wqkvb, bq, bk, bv, QSCALE, qkv, MTOK, 3 * DIMSZ, DIMSZ);

    // fused attention -> aob (bf16, chunk-swizzled for the final GEMM)
    attn_kernel<<<512, 512, 0, stream>>>(qkv, mask, aob);

    // output projection: [4096,1024] @ [1024,1024]^T -> [4096,1024] fp32
    gemm_glds<2, 1><<<(MTOK / 128) * (DIMSZ / 64), 256, 0, stream>>>(
        aob, wob, bo, bo, bo, 1.f, out, MTOK, DIMSZ, DIMSZ);
}